// Round 19
// baseline (285.205 us; speedup 1.0000x reference)
//
#include <hip/hip_runtime.h>

#define N_NODES 4096
#define M_EDGES 4096
#define NNZ_K   262144
#define NCH     4
#define DIM     128
#define KDIM    512               // NCH*DIM
#define NM      (N_NODES * M_EDGES)
#define NUM_ADD 26214             // max(1, int(0.1*NNZ))
#define NCB     2048              // coarse bins over [-1, 1]
#define NFB     32768             // fine fp64 bins over the band
#define NSEG    8                 // sharded candidate cursors
#define SEGSTR  16                // u64 stride between cursors = 128B (own cache line)
#define CAPSEG  32768             // band capacity per segment (8x expected)
#define CAPSEG2 16384             // certain capacity per segment

// ---- workspace layout (byte offsets) ----
#define EXD_OFF   0ull                 // double[M*D]        4 MB
#define AFC_OFF   4194304ull           // bf16[N*512]        4 MB
#define BFC_OFF   8388608ull           // bf16[M*512]        4 MB
#define BKT_OFF   12582912ull          // int[NNZ]           1 MB
#define CVAL_OFF  13631488ull          // double[NSEG*CAPSEG] 2 MB
#define CIDX_OFF  15728640ull          // int[NSEG*CAPSEG]   1 MB
#define CNT_OFF   17039360ull          // int[4096]  (zeroed region starts here)
#define OFFS_OFF  17055744ull          // int[4097]
#define CUR_OFF   17072132ull          // int[4096]
#define HIST_OFF  17088516ull          // int[NCB]
#define FHIST_OFF 17096708ull          // int[NFB] 128 KB
#define SCL_OFF   17227784ull          // int[16] {bstar,G1,-,-,fstar,G1f} (8B-aligned)
#define SEGC_OFF  17227848ull          // u64[NSEG*SEGSTR] 1 KB, one line per cursor (zeroed)
#define ZERO_BYTES (17228872ull - CNT_OFF)
#define NINV_OFF  17228928ull          // double[N*NCH] 128 KB (written by k_fc)
#define EINV_OFF  17360000ull          // double[M*NCH] 128 KB
#define CIDX2_OFF 17491072ull          // int[NSEG*CAPSEG2] 512 KB

typedef short bf16x8 __attribute__((ext_vector_type(8)));
typedef float f32x4  __attribute__((ext_vector_type(4)));

// async global->LDS DMA, width 16B: LDS dest = wave-uniform base + lane*16
#define GLOAD_LDS16(gsrc, ldst)                                                 \
    __builtin_amdgcn_global_load_lds(                                           \
        (const __attribute__((address_space(1))) void*)(gsrc),                  \
        (__attribute__((address_space(3))) void*)(ldst), 16, 0, 0)

__device__ __forceinline__ int bin_c(float s) {
    int b = (int)floorf((s + 1.0f) * 1024.0f);
    return min(max(b, 0), NCB - 1);
}

// fine fp64 binning over [L(b*-12), L(b*-12)+28h); band [b*-11,b*+10] maps inside
__device__ __forceinline__ int fbin_of(double v, int bstar) {
    double lo = (double)(bstar - 12) * (2.0 / 2048.0) - 1.0;
    double wd = (28.0 * (2.0 / 2048.0)) / (double)NFB;
    int f = (int)floor((v - lo) / wd);
    return min(max(f, 0), NFB - 1);
}

// st_mask = (hard - soft) + soft == hard EXACTLY in fp32 (Sterbenz).
__device__ __forceinline__ float hard_mask(float p, float e) {
    float logit = logf(e) - logf(1.0f - e) + logf(p + 1e-8f) - logf(1.0f - p + 1e-8f);
    float soft  = 1.0f / (1.0f + expf(-2.0f * logit));   // sigmoid(logit/TEMP), TEMP=0.5
    return (soft > 0.5f) ? 1.0f : 0.0f;
}

__device__ __forceinline__ unsigned short to_bf16_rtne(float f) {
    unsigned int b = __float_as_uint(f);
    b += 0x7FFFu + ((b >> 16) & 1u);
    return (unsigned short)(b >> 16);
}

// ---- 1. per-edge counts ----
__global__ void k_count(const int* __restrict__ E, int* __restrict__ cnt) {
    int k = blockIdx.x * 256 + threadIdx.x;
    if (k < NNZ_K) atomicAdd(&cnt[E[k]], 1);
}

// ---- 2. exclusive scan over 4096 counts ----
__global__ __launch_bounds__(256) void k_scan(const int* __restrict__ cnt, int* __restrict__ offs) {
    __shared__ int part[256];
    int t = threadIdx.x;
    int loc[16]; int s = 0;
    for (int j = 0; j < 16; ++j) { loc[j] = cnt[t * 16 + j]; s += loc[j]; }
    part[t] = s;
    __syncthreads();
    if (t == 0) { int acc = 0; for (int i = 0; i < 256; ++i) { int v = part[i]; part[i] = acc; acc += v; } }
    __syncthreads();
    int acc = part[t];
    for (int j = 0; j < 16; ++j) { offs[t * 16 + j] = acc; acc += loc[j]; }
    if (t == 255) offs[4096] = acc;
}

// ---- 3. bucket fill ----
__global__ void k_fill(const int* __restrict__ E, const int* __restrict__ offs,
                       int* __restrict__ cur, int* __restrict__ bkt) {
    int k = blockIdx.x * 256 + threadIdx.x;
    if (k < NNZ_K) {
        int e = E[k];
        int pos = atomicAdd(&cur[e], 1);
        bkt[offs[e] + pos] = k;
    }
}

// ---- 4. deterministic scatter-mean (fp64) ----
__global__ __launch_bounds__(128) void k_edge_mean(
        const int* __restrict__ Vv, const int* __restrict__ cnt,
        const int* __restrict__ offs, const int* __restrict__ bkt,
        const float* __restrict__ X, double* __restrict__ eXd) {
    __shared__ int sk[1024];
    __shared__ int sv[1024];
    int m = blockIdx.x;
    int c = cnt[m]; if (c > 1024) c = 1024;
    int off = offs[m];
    for (int t = threadIdx.x; t < c; t += 128) sk[t] = bkt[off + t];
    __syncthreads();
    for (int t = threadIdx.x; t < c; t += 128) {   // rank sort (keys distinct)
        int key = sk[t]; int r = 0;
        for (int j = 0; j < c; ++j) r += (sk[j] < key);
        sv[r] = Vv[key];
    }
    __syncthreads();
    int d = threadIdx.x;
    double s = 0.0;
    for (int j = 0; j < c; ++j) s += (double)X[sv[j] * DIM + d];
    eXd[m * DIM + d] = s / (double)(c > 1 ? c : 1);
}

// ---- 5. per-channel L2-normalized features -> bf16; also store 1/denom ----
template <typename T>
__global__ __launch_bounds__(128) void k_fc(const T* __restrict__ in,
                                            const float* __restrict__ w,
                                            unsigned short* __restrict__ out,
                                            double* __restrict__ dinv) {
    __shared__ double red[128];
    int n = blockIdx.x, d = threadIdx.x;
    double x = (double)in[n * DIM + d];
    for (int c = 0; c < NCH; ++c) {
        double v = x * (double)w[c * DIM + d];
        red[d] = v * v;
        __syncthreads();
        for (int s = 64; s > 0; s >>= 1) { if (d < s) red[d] += red[d + s]; __syncthreads(); }
        double denom = fmax(sqrt(red[0]), 1e-12);
        __syncthreads();
        out[n * KDIM + c * DIM + d] = to_bf16_rtne((float)(v / denom));
        if (d == 0) dinv[n * NCH + c] = 1.0 / denom;
    }
}

// ---- 6. bf16 MFMA GEMM, m97 structure + XOR slot-swizzle (rule #21 pattern):
//      LDS writes stay linear (gload_lds); global SOURCE slot pre-swizzled;
//      ds_read uses the same involution s ^= swz(row), swz(r)=(r&3)^((r>>2)&3).
//      Breaks the 8-way bank conflict (2.1M/dispatch) down to free 2-way.
__global__ __launch_bounds__(256) void k_gemm_mfma(const unsigned short* __restrict__ A,
                                                   const unsigned short* __restrict__ B,
                                                   float* __restrict__ S) {
    __shared__ short As[128][32];   // linear rows of 64B; 4 x 16B slots per row
    __shared__ short Bs[128][32];
    int tid = threadIdx.x;
    int row0 = blockIdx.y * 128, col0 = blockIdx.x * 128;
    int w = tid >> 6, l = tid & 63;
    int wr = (w >> 1) * 64, wc = (w & 1) * 64;
    f32x4 acc[4][4] = {};
    // staging: lane l writes LDS row rb+(l>>2), physical slot l&3.
    // source must hold logical slot (l&3) ^ swz(row); rb%16==0 ->
    // swz(rb+lrow) = ((l>>2)&3) ^ ((l>>4)&3).
    int lrow = l >> 2;
    int lswz = ((l >> 2) & 3) ^ ((l >> 4) & 3);
    int lcol = ((l & 3) ^ lswz) * 8;
    int rb0 = (w * 2 + 0) * 16, rb1 = (w * 2 + 1) * 16;
    const unsigned short* sA0 = A + (size_t)(row0 + rb0 + lrow) * KDIM + lcol;
    const unsigned short* sA1 = A + (size_t)(row0 + rb1 + lrow) * KDIM + lcol;
    const unsigned short* sB0 = B + (size_t)(col0 + rb0 + lrow) * KDIM + lcol;
    const unsigned short* sB1 = B + (size_t)(col0 + rb1 + lrow) * KDIM + lcol;
    // read: lane l reads rows R = base + (l&15); swz(R) = (l&3) ^ ((l>>2)&3);
    // logical slot l>>4 -> physical slot (l>>4) ^ swz(R).
    int swzr = (l & 3) ^ ((l >> 2) & 3);
    int kq = (((l >> 4) ^ swzr) & 3) * 8;
    for (int k0 = 0; k0 < KDIM; k0 += 32) {
        __syncthreads();                       // previous tile fully consumed
        GLOAD_LDS16(sA0 + k0, &As[rb0][0]);
        GLOAD_LDS16(sA1 + k0, &As[rb1][0]);
        GLOAD_LDS16(sB0 + k0, &Bs[rb0][0]);
        GLOAD_LDS16(sB1 + k0, &Bs[rb1][0]);
        __syncthreads();                       // drains vmcnt before barrier
        bf16x8 af[4], bfr[4];
        #pragma unroll
        for (int m = 0; m < 4; ++m) af[m] = *(const bf16x8*)&As[wr + m * 16 + (l & 15)][kq];
        #pragma unroll
        for (int n = 0; n < 4; ++n) bfr[n] = *(const bf16x8*)&Bs[wc + n * 16 + (l & 15)][kq];
        #pragma unroll
        for (int m = 0; m < 4; ++m)
            #pragma unroll
            for (int n = 0; n < 4; ++n)
                acc[m][n] = __builtin_amdgcn_mfma_f32_16x16x32_bf16(af[m], bfr[n], acc[m][n], 0, 0, 0);
    }
    #pragma unroll
    for (int m = 0; m < 4; ++m) {
        int r = row0 + wr + m * 16 + (l >> 4) * 4;
        #pragma unroll
        for (int n = 0; n < 4; ++n) {
            int c = col0 + wc + n * 16 + (l & 15);
            #pragma unroll
            for (int j = 0; j < 4; ++j)
                S[(size_t)(r + j) * M_EDGES + c] = 0.25f * acc[m][n][j];
        }
    }
}

// ---- 7. mask incidences: plain store (idempotent under duplicates) ----
__global__ void k_mask(const int* __restrict__ Vv, const int* __restrict__ E,
                       float* __restrict__ S) {
    int k = blockIdx.x * 256 + threadIdx.x;
    if (k < NNZ_K) S[(size_t)Vv[k] * M_EDGES + E[k]] = -1e30f;
}

// ---- 8. coarse histogram, 4 lane-interleaved int LDS copies ----
__global__ __launch_bounds__(256) void k_hist_coarse(const float4* __restrict__ S4,
                                                     int* __restrict__ hist) {
    __shared__ int h[4][NCB + 8];   // +8 pad: copies land on distinct banks
    int t = threadIdx.x;
    for (int i = t; i < 4 * (NCB + 8); i += 256) ((int*)h)[i] = 0;
    __syncthreads();
    int* hc = h[t & 3];
    int stride = gridDim.x * 256;
    for (int i = blockIdx.x * 256 + t; i < NM / 4; i += stride) {
        float4 v = S4[i];
        if (v.x > -2.0f) atomicAdd(&hc[bin_c(v.x)], 1);
        if (v.y > -2.0f) atomicAdd(&hc[bin_c(v.y)], 1);
        if (v.z > -2.0f) atomicAdd(&hc[bin_c(v.z)], 1);
        if (v.w > -2.0f) atomicAdd(&hc[bin_c(v.w)], 1);
    }
    __syncthreads();
    for (int i = t; i < NCB; i += 256) {
        int s = h[0][i] + h[1][i] + h[2][i] + h[3][i];
        if (s) atomicAdd(&hist[i], s);
    }
}

// ---- 9. find cutoff bin b*, then G1 = count(bin >= b*+11) ----
__global__ __launch_bounds__(256) void k_findcut(const int* __restrict__ hist, int* __restrict__ scl) {
    __shared__ int part[256];
    __shared__ int sb;
    int t = threadIdx.x;
    int loc[8]; int s = 0;
    for (int j = 0; j < 8; ++j) { loc[j] = hist[t * 8 + j]; s += loc[j]; }
    part[t] = s;
    __syncthreads();
    if (t == 0) { int acc = 0; for (int i = 255; i >= 0; --i) { int v = part[i]; part[i] = acc; acc += v; } }
    __syncthreads();
    int run = part[t];
    for (int j = 7; j >= 0; --j) {
        int h = loc[j];
        run += h;
        if (run >= NUM_ADD && run - h < NUM_ADD) { scl[0] = t * 8 + j; sb = t * 8 + j; }
    }
    __syncthreads();
    int bstar = sb;
    int g = 0;
    for (int i = bstar + 11 + t; i < NCB; i += 256) g += hist[i];
    part[t] = g;
    __syncthreads();
    for (int st2 = 128; st2 > 0; st2 >>= 1) { if (t < st2) part[t] += part[t + st2]; __syncthreads(); }
    if (t == 0) scl[1] = part[0];    // G1: certainly-selected (exact integer count)
}

// ---- 10. barrier-free collect, 8 cursors on 8 DISTINCT cache lines + fused zeroing ----
__global__ __launch_bounds__(256) void k_collect(float4* __restrict__ S4,
        const int* __restrict__ scl, unsigned long long* __restrict__ segc,
        int* __restrict__ cidx, int* __restrict__ cidx2) {
    __shared__ unsigned short buf1[4096];
    __shared__ unsigned short buf2[4096];
    __shared__ int c1, c2;
    __shared__ unsigned long long gbase;
    int t = threadIdx.x;
    if (t == 0) { c1 = 0; c2 = 0; }
    __syncthreads();
    int bstar = scl[0];
    size_t base4 = (size_t)blockIdx.x * 1024 + t;    // float4 units
    float4 v0 = S4[base4];
    float4 v1 = S4[base4 + 256];
    float4 v2 = S4[base4 + 512];
    float4 v3 = S4[base4 + 768];
    // local float offset of component c of quad q: (t + q*256)*4 + c  (< 4096)
    #define COLLECT1(sc, loc)                                                   \
        if ((sc) > -2.0f) {                                                     \
            int b = bin_c(sc);                                                  \
            if (b >= bstar + 11)      buf2[atomicAdd(&c2, 1)] = (unsigned short)(loc); \
            else if (b >= bstar - 11) buf1[atomicAdd(&c1, 1)] = (unsigned short)(loc); \
        }
    #define COLLECT4(v, q)                                                      \
        COLLECT1((v).x, (t + (q)*256) * 4 + 0) COLLECT1((v).y, (t + (q)*256) * 4 + 1) \
        COLLECT1((v).z, (t + (q)*256) * 4 + 2) COLLECT1((v).w, (t + (q)*256) * 4 + 3)
    COLLECT4(v0, 0) COLLECT4(v1, 1) COLLECT4(v2, 2) COLLECT4(v3, 3)
    #undef COLLECT4
    #undef COLLECT1
    // zero own chunk (plain stores; measured free vs read-only in rounds 12/16)
    float4 z = make_float4(0.f, 0.f, 0.f, 0.f);
    S4[base4] = z; S4[base4 + 256] = z; S4[base4 + 512] = z; S4[base4 + 768] = z;
    __syncthreads();                 // counts final
    int seg = blockIdx.x & (NSEG - 1);
    if (t == 0) {
        unsigned long long pack = (unsigned long long)(unsigned)c1
                                | ((unsigned long long)(unsigned)c2 << 32);
        gbase = atomicAdd(&segc[seg * SEGSTR], pack);
    }
    __syncthreads();                 // gbase visible
    int g1 = (int)(gbase & 0xffffffffull);
    int g2 = (int)(gbase >> 32);
    int gb = blockIdx.x * 4096;
    int* ci1 = cidx  + seg * CAPSEG;
    int* ci2 = cidx2 + seg * CAPSEG2;
    for (int j = t; j < c1; j += 256) { int g = g1 + j; if (g < CAPSEG)  ci1[g] = gb + buf1[j]; }
    for (int j = t; j < c2; j += 256) { int g = g2 + j; if (g < CAPSEG2) ci2[g] = gb + buf2[j]; }
}

// ---- 11. scatter hard mask at (V,E) positions (H=1 there; out is 0 elsewhere) ----
__global__ void k_scatter(const int* __restrict__ Vv, const int* __restrict__ E,
                          const float* __restrict__ prob, const float* __restrict__ eps,
                          float* __restrict__ out) {
    int k = blockIdx.x * 256 + threadIdx.x;
    if (k < NNZ_K) {
        size_t idx = (size_t)Vv[k] * M_EDGES + E[k];
        out[idx] = hard_mask(prob[idx], eps[idx]);
    }
}

// ---- 12. scatter-write certain entries, per segment ----
__global__ __launch_bounds__(256) void k_selc(const unsigned long long* __restrict__ segc,
        const int* __restrict__ cidx2,
        const float* __restrict__ prob, const float* __restrict__ eps,
        float* __restrict__ out) {
    for (int s = 0; s < NSEG; ++s) {
        int c2 = (int)(segc[s * SEGSTR] >> 32); if (c2 > CAPSEG2) c2 = CAPSEG2;
        const int* ci = cidx2 + s * CAPSEG2;
        for (int i = blockIdx.x * 256 + threadIdx.x; i < c2; i += 256 * 128) {
            int idx = ci[i];
            out[idx] = hard_mask(prob[idx], eps[idx]);
        }
    }
}

// ---- 13. exact fp64 band values, wave-per-candidate, cross-terms only ----
__global__ __launch_bounds__(256) void k_exact(
        const unsigned long long* __restrict__ segc, const int* __restrict__ cidx,
        double* __restrict__ cval,
        const float* __restrict__ X, const double* __restrict__ eXd, const float* __restrict__ cw,
        const double* __restrict__ ninv, const double* __restrict__ einv) {
    int wid = (blockIdx.x * 256 + threadIdx.x) >> 6;
    int l = threadIdx.x & 63;
    int nw = gridDim.x * 4;
    double w2[NCH][2];                       // hoisted: uniform across candidates
    #pragma unroll
    for (int c = 0; c < NCH; ++c) {
        float2 wc2 = *(const float2*)&cw[c * DIM + 2 * l];
        w2[c][0] = (double)wc2.x * (double)wc2.x;
        w2[c][1] = (double)wc2.y * (double)wc2.y;
    }
    for (int s = 0; s < NSEG; ++s) {
        int nc = (int)(segc[s * SEGSTR] & 0xffffffffull); if (nc > CAPSEG) nc = CAPSEG;
        const int* ci = cidx + s * CAPSEG;
        double* cv = cval + s * CAPSEG;
        for (int i = wid; i < nc; i += nw) {
            int idx = ci[i];
            int n = idx >> 12, m = idx & (M_EDGES - 1);
            float2  x2 = *(const float2*)&X[n * DIM + 2 * l];
            double2 e2 = *(const double2*)&eXd[m * DIM + 2 * l];
            double p0 = (double)x2.x * e2.x;
            double p1 = (double)x2.y * e2.y;
            double dt0 = p0 * w2[0][0] + p1 * w2[0][1];
            double dt1 = p0 * w2[1][0] + p1 * w2[1][1];
            double dt2 = p0 * w2[2][0] + p1 * w2[2][1];
            double dt3 = p0 * w2[3][0] + p1 * w2[3][1];
            #pragma unroll
            for (int sh = 1; sh < 64; sh <<= 1) {
                dt0 += __shfl_xor(dt0, sh);
                dt1 += __shfl_xor(dt1, sh);
                dt2 += __shfl_xor(dt2, sh);
                dt3 += __shfl_xor(dt3, sh);
            }
            if (l == 0) {
                const double* nv = &ninv[n * NCH];
                const double* ev = &einv[m * NCH];
                cv[i] = 0.25 * (dt0 * nv[0] * ev[0] + dt1 * nv[1] * ev[1]
                              + dt2 * nv[2] * ev[2] + dt3 * nv[3] * ev[3]);
            }
        }
    }
}

// ---- 14. fine fp64 histogram of band values, per segment ----
__global__ __launch_bounds__(256) void k_fhist(const unsigned long long* __restrict__ segc,
                                               const double* __restrict__ cval,
                                               const int* __restrict__ scl,
                                               int* __restrict__ fh) {
    int bstar = scl[0];
    for (int s = 0; s < NSEG; ++s) {
        int nc = (int)(segc[s * SEGSTR] & 0xffffffffull); if (nc > CAPSEG) nc = CAPSEG;
        const double* cv = cval + s * CAPSEG;
        for (int i = blockIdx.x * 256 + threadIdx.x; i < nc; i += 256 * 256)
            atomicAdd(&fh[fbin_of(cv[i], bstar)], 1);
    }
}

// ---- 15. find fine cutoff f* for target T = NUM_ADD - G1 ----
__global__ __launch_bounds__(1024) void k_ffind(const int* __restrict__ fh, int* __restrict__ scl) {
    __shared__ int part[1024];
    int T = NUM_ADD - scl[1];            // >= 1 by construction of b*
    int t = threadIdx.x;
    int loc[32]; int s = 0;
    for (int j = 0; j < 32; ++j) { loc[j] = fh[t * 32 + j]; s += loc[j]; }
    part[t] = s;
    __syncthreads();
    if (t == 0) { int acc = 0; for (int i = 1023; i >= 0; --i) { int v = part[i]; part[i] = acc; acc += v; } }
    __syncthreads();
    int run = part[t];
    for (int j = 31; j >= 0; --j) {
        int h = loc[j];
        run += h;
        if (run >= T && run - h < T) { scl[4] = t * 32 + j; scl[5] = run - h; }
    }
}

// ---- 16. write band candidates strictly above the fine cutoff bin ----
__global__ __launch_bounds__(256) void k_write(
        const unsigned long long* __restrict__ segc, const int* __restrict__ cidx,
        const double* __restrict__ cval, const int* __restrict__ scl,
        const float* __restrict__ prob, const float* __restrict__ eps,
        float* __restrict__ out) {
    int fs = scl[4], bstar = scl[0];
    for (int s = 0; s < NSEG; ++s) {
        int nc = (int)(segc[s * SEGSTR] & 0xffffffffull); if (nc > CAPSEG) nc = CAPSEG;
        const int* ci = cidx + s * CAPSEG;
        const double* cv = cval + s * CAPSEG;
        for (int i = blockIdx.x * 256 + threadIdx.x; i < nc; i += 256 * 256) {
            if (fbin_of(cv[i], bstar) > fs) {
                int idx = ci[i];
                out[idx] = hard_mask(prob[idx], eps[idx]);
            }
        }
    }
}

// ---- 17. exact tie-break inside the single ambiguous fine bin ----
__global__ __launch_bounds__(256) void k_tie(
        const unsigned long long* __restrict__ segc, const int* __restrict__ cidx,
        const double* __restrict__ cval, const int* __restrict__ scl,
        const float* __restrict__ prob, const float* __restrict__ eps,
        float* __restrict__ out) {
    __shared__ double mv[256];
    __shared__ int    mi[256];
    __shared__ int    cnt;
    int T = NUM_ADD - scl[1];
    int fs = scl[4], G1f = scl[5], bstar = scl[0];
    int t = threadIdx.x;
    if (t == 0) cnt = 0;
    __syncthreads();
    for (int s = 0; s < NSEG; ++s) {
        int nc = (int)(segc[s * SEGSTR] & 0xffffffffull); if (nc > CAPSEG) nc = CAPSEG;
        const double* cv = cval + s * CAPSEG;
        const int* ci = cidx + s * CAPSEG;
        for (int i = t; i < nc; i += 256) {
            if (fbin_of(cv[i], bstar) == fs) {
                int sl = atomicAdd(&cnt, 1);
                if (sl < 256) { mv[sl] = cv[i]; mi[sl] = ci[i]; }
            }
        }
    }
    __syncthreads();
    int nm = min(cnt, 256);
    for (int k = t; k < nm; k += 256) {
        double v = mv[k]; int idx = mi[k];
        int rank = G1f;
        for (int j = 0; j < nm; ++j)
            rank += (mv[j] > v || (mv[j] == v && mi[j] < idx)) ? 1 : 0;
        if (rank < T)
            out[idx] = hard_mask(prob[idx], eps[idx]);
    }
}

extern "C" void kernel_launch(void* const* d_in, const int* in_sizes, int n_in,
                              void* d_out, int out_size, void* d_ws, size_t ws_size,
                              hipStream_t stream) {
    const float* X    = (const float*)d_in[0];
    const int*   Vv   = (const int*)d_in[2];
    const int*   E    = (const int*)d_in[3];
    const float* prob = (const float*)d_in[4];
    const float* cw   = (const float*)d_in[5];
    const float* eps  = (const float*)d_in[6];
    float* out = (float*)d_out;
    char*  ws  = (char*)d_ws;

    double*             eXd   = (double*)(ws + EXD_OFF);
    unsigned short*     Afc   = (unsigned short*)(ws + AFC_OFF);
    unsigned short*     Bfc   = (unsigned short*)(ws + BFC_OFF);
    int*                bkt   = (int*)(ws + BKT_OFF);
    double*             cval  = (double*)(ws + CVAL_OFF);
    int*                cidx  = (int*)(ws + CIDX_OFF);
    int*                cidx2 = (int*)(ws + CIDX2_OFF);
    int*                cnt   = (int*)(ws + CNT_OFF);
    int*                offs  = (int*)(ws + OFFS_OFF);
    int*                cur   = (int*)(ws + CUR_OFF);
    int*                hist  = (int*)(ws + HIST_OFF);
    int*                fh    = (int*)(ws + FHIST_OFF);
    int*                scl   = (int*)(ws + SCL_OFF);
    unsigned long long* segc  = (unsigned long long*)(ws + SEGC_OFF);
    double*             ninv  = (double*)(ws + NINV_OFF);
    double*             einv  = (double*)(ws + EINV_OFF);

    hipMemsetAsync(ws + CNT_OFF, 0, (size_t)ZERO_BYTES, stream);

    k_count<<<NNZ_K / 256, 256, 0, stream>>>(E, cnt);
    k_scan<<<1, 256, 0, stream>>>(cnt, offs);
    k_fill<<<NNZ_K / 256, 256, 0, stream>>>(E, offs, cur, bkt);
    k_edge_mean<<<M_EDGES, 128, 0, stream>>>(Vv, cnt, offs, bkt, X, eXd);
    k_fc<float><<<N_NODES, 128, 0, stream>>>(X, cw, Afc, ninv);
    k_fc<double><<<M_EDGES, 128, 0, stream>>>(eXd, cw, Bfc, einv);
    dim3 gg(M_EDGES / 128, N_NODES / 128);
    k_gemm_mfma<<<gg, 256, 0, stream>>>(Afc, Bfc, out);
    k_mask<<<NNZ_K / 256, 256, 0, stream>>>(Vv, E, out);
    k_hist_coarse<<<1024, 256, 0, stream>>>((const float4*)out, hist);
    k_findcut<<<1, 256, 0, stream>>>(hist, scl);
    k_collect<<<4096, 256, 0, stream>>>((float4*)out, scl, segc, cidx, cidx2);
    k_scatter<<<NNZ_K / 256, 256, 0, stream>>>(Vv, E, prob, eps, out);
    k_selc<<<128, 256, 0, stream>>>(segc, cidx2, prob, eps, out);
    k_exact<<<1024, 256, 0, stream>>>(segc, cidx, cval, X, eXd, cw, ninv, einv);
    k_fhist<<<256, 256, 0, stream>>>(segc, cval, scl, fh);
    k_ffind<<<1, 1024, 0, stream>>>(fh, scl);
    k_write<<<256, 256, 0, stream>>>(segc, cidx, cval, scl, prob, eps, out);
    k_tie<<<1, 256, 0, stream>>>(segc, cidx, cval, scl, prob, eps, out);
}

// Round 20
// 281.007 us; speedup vs baseline: 1.0149x; 1.0149x over previous
//
#include <hip/hip_runtime.h>

#define N_NODES 4096
#define M_EDGES 4096
#define NNZ_K   262144
#define NCH     4
#define DIM     128
#define KDIM    512               // NCH*DIM
#define NM      (N_NODES * M_EDGES)
#define NUM_ADD 26214             // max(1, int(0.1*NNZ))
#define NCB     2048              // coarse bins over [-1, 1]
#define NFB     32768             // fine fp64 bins over the band
#define NSEG    8                 // sharded candidate cursors
#define SEGSTR  16                // u64 stride between cursors = 128B (own cache line)
#define CAPSEG  32768             // band capacity per segment (8x expected)
#define CAPSEG2 16384             // certain capacity per segment

// ---- workspace layout (byte offsets) ----
#define EXD_OFF   0ull                 // double[M*D]        4 MB
#define AFC_OFF   4194304ull           // bf16[N*512]        4 MB
#define BFC_OFF   8388608ull           // bf16[M*512]        4 MB
#define BKT_OFF   12582912ull          // int[NNZ]           1 MB
#define CVAL_OFF  13631488ull          // double[NSEG*CAPSEG] 2 MB
#define CIDX_OFF  15728640ull          // int[NSEG*CAPSEG]   1 MB
#define CNT_OFF   17039360ull          // int[4096]  (zeroed region starts here)
#define OFFS_OFF  17055744ull          // int[4097]
#define CUR_OFF   17072132ull          // int[4096]
#define HIST_OFF  17088516ull          // int[NCB]
#define FHIST_OFF 17096708ull          // int[NFB] 128 KB
#define SCL_OFF   17227784ull          // int[16] {bstar,G1,-,-,fstar,G1f} (8B-aligned)
#define SEGC_OFF  17227848ull          // u64[NSEG*SEGSTR] 1 KB, one line per cursor (zeroed)
#define ZERO_BYTES (17228872ull - CNT_OFF)
#define NINV_OFF  17228928ull          // double[N*NCH] 128 KB (written by k_fc)
#define EINV_OFF  17360000ull          // double[M*NCH] 128 KB
#define CIDX2_OFF 17491072ull          // int[NSEG*CAPSEG2] 512 KB

typedef short bf16x8 __attribute__((ext_vector_type(8)));
typedef float f32x4  __attribute__((ext_vector_type(4)));

// async global->LDS DMA, width 16B: LDS dest = wave-uniform base + lane*16
#define GLOAD_LDS16(gsrc, ldst)                                                 \
    __builtin_amdgcn_global_load_lds(                                           \
        (const __attribute__((address_space(1))) void*)(gsrc),                  \
        (__attribute__((address_space(3))) void*)(ldst), 16, 0, 0)

__device__ __forceinline__ int bin_c(float s) {
    int b = (int)floorf((s + 1.0f) * 1024.0f);
    return min(max(b, 0), NCB - 1);
}

// fine fp64 binning over [L(b*-12), L(b*-12)+28h); band [b*-11,b*+10] maps inside
__device__ __forceinline__ int fbin_of(double v, int bstar) {
    double lo = (double)(bstar - 12) * (2.0 / 2048.0) - 1.0;
    double wd = (28.0 * (2.0 / 2048.0)) / (double)NFB;
    int f = (int)floor((v - lo) / wd);
    return min(max(f, 0), NFB - 1);
}

// st_mask = (hard - soft) + soft == hard EXACTLY in fp32 (Sterbenz).
__device__ __forceinline__ float hard_mask(float p, float e) {
    float logit = logf(e) - logf(1.0f - e) + logf(p + 1e-8f) - logf(1.0f - p + 1e-8f);
    float soft  = 1.0f / (1.0f + expf(-2.0f * logit));   // sigmoid(logit/TEMP), TEMP=0.5
    return (soft > 0.5f) ? 1.0f : 0.0f;
}

__device__ __forceinline__ unsigned short to_bf16_rtne(float f) {
    unsigned int b = __float_as_uint(f);
    b += 0x7FFFu + ((b >> 16) & 1u);
    return (unsigned short)(b >> 16);
}

// ---- 1. per-edge counts ----
__global__ void k_count(const int* __restrict__ E, int* __restrict__ cnt) {
    int k = blockIdx.x * 256 + threadIdx.x;
    if (k < NNZ_K) atomicAdd(&cnt[E[k]], 1);
}

// ---- 2. exclusive scan over 4096 counts ----
__global__ __launch_bounds__(256) void k_scan(const int* __restrict__ cnt, int* __restrict__ offs) {
    __shared__ int part[256];
    int t = threadIdx.x;
    int loc[16]; int s = 0;
    for (int j = 0; j < 16; ++j) { loc[j] = cnt[t * 16 + j]; s += loc[j]; }
    part[t] = s;
    __syncthreads();
    if (t == 0) { int acc = 0; for (int i = 0; i < 256; ++i) { int v = part[i]; part[i] = acc; acc += v; } }
    __syncthreads();
    int acc = part[t];
    for (int j = 0; j < 16; ++j) { offs[t * 16 + j] = acc; acc += loc[j]; }
    if (t == 255) offs[4096] = acc;
}

// ---- 3. bucket fill ----
__global__ void k_fill(const int* __restrict__ E, const int* __restrict__ offs,
                       int* __restrict__ cur, int* __restrict__ bkt) {
    int k = blockIdx.x * 256 + threadIdx.x;
    if (k < NNZ_K) {
        int e = E[k];
        int pos = atomicAdd(&cur[e], 1);
        bkt[offs[e] + pos] = k;
    }
}

// ---- 4. deterministic scatter-mean (fp64) ----
__global__ __launch_bounds__(128) void k_edge_mean(
        const int* __restrict__ Vv, const int* __restrict__ cnt,
        const int* __restrict__ offs, const int* __restrict__ bkt,
        const float* __restrict__ X, double* __restrict__ eXd) {
    __shared__ int sk[1024];
    __shared__ int sv[1024];
    int m = blockIdx.x;
    int c = cnt[m]; if (c > 1024) c = 1024;
    int off = offs[m];
    for (int t = threadIdx.x; t < c; t += 128) sk[t] = bkt[off + t];
    __syncthreads();
    for (int t = threadIdx.x; t < c; t += 128) {   // rank sort (keys distinct)
        int key = sk[t]; int r = 0;
        for (int j = 0; j < c; ++j) r += (sk[j] < key);
        sv[r] = Vv[key];
    }
    __syncthreads();
    int d = threadIdx.x;
    double s = 0.0;
    for (int j = 0; j < c; ++j) s += (double)X[sv[j] * DIM + d];
    eXd[m * DIM + d] = s / (double)(c > 1 ? c : 1);
}

// ---- 5. per-channel L2-normalized features -> bf16; also store 1/denom ----
template <typename T>
__global__ __launch_bounds__(128) void k_fc(const T* __restrict__ in,
                                            const float* __restrict__ w,
                                            unsigned short* __restrict__ out,
                                            double* __restrict__ dinv) {
    __shared__ double red[128];
    int n = blockIdx.x, d = threadIdx.x;
    double x = (double)in[n * DIM + d];
    for (int c = 0; c < NCH; ++c) {
        double v = x * (double)w[c * DIM + d];
        red[d] = v * v;
        __syncthreads();
        for (int s = 64; s > 0; s >>= 1) { if (d < s) red[d] += red[d + s]; __syncthreads(); }
        double denom = fmax(sqrt(red[0]), 1e-12);
        __syncthreads();
        out[n * KDIM + c * DIM + d] = to_bf16_rtne((float)(v / denom));
        if (d == 0) dinv[n * NCH + c] = 1.0 / denom;
    }
}

// ---- 6. bf16 MFMA GEMM, BK=64: 8 K-steps (16 barrier drains vs 32).
//      128B rows are bank-period aligned -> slot-XOR involution required:
//      stage source logical slot (l&7)^(l>>3); read physical (kk*4+q)^(l&7).
//      MFMA K-order unchanged -> S bit-identical.
__global__ __launch_bounds__(256) void k_gemm_mfma(const unsigned short* __restrict__ A,
                                                   const unsigned short* __restrict__ B,
                                                   float* __restrict__ S) {
    __shared__ short As[128][64];   // 16 KB each; rows = 128B = 8 x 16B slots
    __shared__ short Bs[128][64];
    int tid = threadIdx.x;
    int row0 = blockIdx.y * 128, col0 = blockIdx.x * 128;
    int w = tid >> 6, l = tid & 63;
    int wr = (w >> 1) * 64, wc = (w & 1) * 64;
    f32x4 acc[4][4] = {};
    // staging: wave w, instr i covers rows w*32+i*8 .. +7; lane l -> row +(l>>3),
    // physical slot l&7; source logical slot = (l&7) ^ (row&7) = (l&7) ^ (l>>3).
    int srow = l >> 3;
    int scol = ((l & 7) ^ srow) * 8;        // shorts
    int rbw = w * 32;
    const unsigned short* gA[4];
    const unsigned short* gB[4];
    #pragma unroll
    for (int i = 0; i < 4; ++i) {
        gA[i] = A + (size_t)(row0 + rbw + i * 8 + srow) * KDIM + scol;
        gB[i] = B + (size_t)(col0 + rbw + i * 8 + srow) * KDIM + scol;
    }
    // read: row R has R&7 = l&7 (wr, m*16 are multiples of 8... R = base + (l&15),
    // (l&15)&7 = l&7); logical slot kk*4+q -> physical (kk*4+q)^(l&7).
    int q = l >> 4;
    int kq0 = ((q ^ (l & 7)) & 7) * 8;          // kk = 0
    int kq1 = (((4 + q) ^ (l & 7)) & 7) * 8;    // kk = 1
    for (int k0 = 0; k0 < KDIM; k0 += 64) {
        __syncthreads();                       // previous tile fully consumed
        #pragma unroll
        for (int i = 0; i < 4; ++i) {
            GLOAD_LDS16(gA[i] + k0, &As[rbw + i * 8][0]);
            GLOAD_LDS16(gB[i] + k0, &Bs[rbw + i * 8][0]);
        }
        __syncthreads();                       // drains vmcnt before barrier
        bf16x8 af0[4], af1[4], bf0[4], bf1[4];
        #pragma unroll
        for (int m = 0; m < 4; ++m) {
            af0[m] = *(const bf16x8*)&As[wr + m * 16 + (l & 15)][kq0];
            af1[m] = *(const bf16x8*)&As[wr + m * 16 + (l & 15)][kq1];
        }
        #pragma unroll
        for (int n = 0; n < 4; ++n) {
            bf0[n] = *(const bf16x8*)&Bs[wc + n * 16 + (l & 15)][kq0];
            bf1[n] = *(const bf16x8*)&Bs[wc + n * 16 + (l & 15)][kq1];
        }
        #pragma unroll
        for (int m = 0; m < 4; ++m)
            #pragma unroll
            for (int n = 0; n < 4; ++n) {
                acc[m][n] = __builtin_amdgcn_mfma_f32_16x16x32_bf16(af0[m], bf0[n], acc[m][n], 0, 0, 0);
                acc[m][n] = __builtin_amdgcn_mfma_f32_16x16x32_bf16(af1[m], bf1[n], acc[m][n], 0, 0, 0);
            }
    }
    #pragma unroll
    for (int m = 0; m < 4; ++m) {
        int r = row0 + wr + m * 16 + (l >> 4) * 4;
        #pragma unroll
        for (int n = 0; n < 4; ++n) {
            int c = col0 + wc + n * 16 + (l & 15);
            #pragma unroll
            for (int j = 0; j < 4; ++j)
                S[(size_t)(r + j) * M_EDGES + c] = 0.25f * acc[m][n][j];
        }
    }
}

// ---- 7. mask incidences: plain store (idempotent under duplicates) ----
__global__ void k_mask(const int* __restrict__ Vv, const int* __restrict__ E,
                       float* __restrict__ S) {
    int k = blockIdx.x * 256 + threadIdx.x;
    if (k < NNZ_K) S[(size_t)Vv[k] * M_EDGES + E[k]] = -1e30f;
}

// ---- 8. coarse histogram, 4 lane-interleaved int LDS copies ----
__global__ __launch_bounds__(256) void k_hist_coarse(const float4* __restrict__ S4,
                                                     int* __restrict__ hist) {
    __shared__ int h[4][NCB + 8];   // +8 pad: copies land on distinct banks
    int t = threadIdx.x;
    for (int i = t; i < 4 * (NCB + 8); i += 256) ((int*)h)[i] = 0;
    __syncthreads();
    int* hc = h[t & 3];
    int stride = gridDim.x * 256;
    for (int i = blockIdx.x * 256 + t; i < NM / 4; i += stride) {
        float4 v = S4[i];
        if (v.x > -2.0f) atomicAdd(&hc[bin_c(v.x)], 1);
        if (v.y > -2.0f) atomicAdd(&hc[bin_c(v.y)], 1);
        if (v.z > -2.0f) atomicAdd(&hc[bin_c(v.z)], 1);
        if (v.w > -2.0f) atomicAdd(&hc[bin_c(v.w)], 1);
    }
    __syncthreads();
    for (int i = t; i < NCB; i += 256) {
        int s = h[0][i] + h[1][i] + h[2][i] + h[3][i];
        if (s) atomicAdd(&hist[i], s);
    }
}

// ---- 9. find cutoff bin b*, then G1 = count(bin >= b*+11) ----
__global__ __launch_bounds__(256) void k_findcut(const int* __restrict__ hist, int* __restrict__ scl) {
    __shared__ int part[256];
    __shared__ int sb;
    int t = threadIdx.x;
    int loc[8]; int s = 0;
    for (int j = 0; j < 8; ++j) { loc[j] = hist[t * 8 + j]; s += loc[j]; }
    part[t] = s;
    __syncthreads();
    if (t == 0) { int acc = 0; for (int i = 255; i >= 0; --i) { int v = part[i]; part[i] = acc; acc += v; } }
    __syncthreads();
    int run = part[t];
    for (int j = 7; j >= 0; --j) {
        int h = loc[j];
        run += h;
        if (run >= NUM_ADD && run - h < NUM_ADD) { scl[0] = t * 8 + j; sb = t * 8 + j; }
    }
    __syncthreads();
    int bstar = sb;
    int g = 0;
    for (int i = bstar + 11 + t; i < NCB; i += 256) g += hist[i];
    part[t] = g;
    __syncthreads();
    for (int st2 = 128; st2 > 0; st2 >>= 1) { if (t < st2) part[t] += part[t + st2]; __syncthreads(); }
    if (t == 0) scl[1] = part[0];    // G1: certainly-selected (exact integer count)
}

// ---- 10. barrier-free collect, 8 cursors on 8 DISTINCT cache lines + fused zeroing ----
__global__ __launch_bounds__(256) void k_collect(float4* __restrict__ S4,
        const int* __restrict__ scl, unsigned long long* __restrict__ segc,
        int* __restrict__ cidx, int* __restrict__ cidx2) {
    __shared__ unsigned short buf1[4096];
    __shared__ unsigned short buf2[4096];
    __shared__ int c1, c2;
    __shared__ unsigned long long gbase;
    int t = threadIdx.x;
    if (t == 0) { c1 = 0; c2 = 0; }
    __syncthreads();
    int bstar = scl[0];
    size_t base4 = (size_t)blockIdx.x * 1024 + t;    // float4 units
    float4 v0 = S4[base4];
    float4 v1 = S4[base4 + 256];
    float4 v2 = S4[base4 + 512];
    float4 v3 = S4[base4 + 768];
    // local float offset of component c of quad q: (t + q*256)*4 + c  (< 4096)
    #define COLLECT1(sc, loc)                                                   \
        if ((sc) > -2.0f) {                                                     \
            int b = bin_c(sc);                                                  \
            if (b >= bstar + 11)      buf2[atomicAdd(&c2, 1)] = (unsigned short)(loc); \
            else if (b >= bstar - 11) buf1[atomicAdd(&c1, 1)] = (unsigned short)(loc); \
        }
    #define COLLECT4(v, q)                                                      \
        COLLECT1((v).x, (t + (q)*256) * 4 + 0) COLLECT1((v).y, (t + (q)*256) * 4 + 1) \
        COLLECT1((v).z, (t + (q)*256) * 4 + 2) COLLECT1((v).w, (t + (q)*256) * 4 + 3)
    COLLECT4(v0, 0) COLLECT4(v1, 1) COLLECT4(v2, 2) COLLECT4(v3, 3)
    #undef COLLECT4
    #undef COLLECT1
    // zero own chunk (plain stores; measured free vs read-only in rounds 12/16)
    float4 z = make_float4(0.f, 0.f, 0.f, 0.f);
    S4[base4] = z; S4[base4 + 256] = z; S4[base4 + 512] = z; S4[base4 + 768] = z;
    __syncthreads();                 // counts final
    int seg = blockIdx.x & (NSEG - 1);
    if (t == 0) {
        unsigned long long pack = (unsigned long long)(unsigned)c1
                                | ((unsigned long long)(unsigned)c2 << 32);
        gbase = atomicAdd(&segc[seg * SEGSTR], pack);
    }
    __syncthreads();                 // gbase visible
    int g1 = (int)(gbase & 0xffffffffull);
    int g2 = (int)(gbase >> 32);
    int gb = blockIdx.x * 4096;
    int* ci1 = cidx  + seg * CAPSEG;
    int* ci2 = cidx2 + seg * CAPSEG2;
    for (int j = t; j < c1; j += 256) { int g = g1 + j; if (g < CAPSEG)  ci1[g] = gb + buf1[j]; }
    for (int j = t; j < c2; j += 256) { int g = g2 + j; if (g < CAPSEG2) ci2[g] = gb + buf2[j]; }
}

// ---- 11. scatter hard mask at (V,E) positions (H=1 there; out is 0 elsewhere) ----
__global__ void k_scatter(const int* __restrict__ Vv, const int* __restrict__ E,
                          const float* __restrict__ prob, const float* __restrict__ eps,
                          float* __restrict__ out) {
    int k = blockIdx.x * 256 + threadIdx.x;
    if (k < NNZ_K) {
        size_t idx = (size_t)Vv[k] * M_EDGES + E[k];
        out[idx] = hard_mask(prob[idx], eps[idx]);
    }
}

// ---- 12. scatter-write certain entries, per segment ----
__global__ __launch_bounds__(256) void k_selc(const unsigned long long* __restrict__ segc,
        const int* __restrict__ cidx2,
        const float* __restrict__ prob, const float* __restrict__ eps,
        float* __restrict__ out) {
    for (int s = 0; s < NSEG; ++s) {
        int c2 = (int)(segc[s * SEGSTR] >> 32); if (c2 > CAPSEG2) c2 = CAPSEG2;
        const int* ci = cidx2 + s * CAPSEG2;
        for (int i = blockIdx.x * 256 + threadIdx.x; i < c2; i += 256 * 128) {
            int idx = ci[i];
            out[idx] = hard_mask(prob[idx], eps[idx]);
        }
    }
}

// ---- 13. exact fp64 band values, wave-per-candidate, cross-terms only ----
__global__ __launch_bounds__(256) void k_exact(
        const unsigned long long* __restrict__ segc, const int* __restrict__ cidx,
        double* __restrict__ cval,
        const float* __restrict__ X, const double* __restrict__ eXd, const float* __restrict__ cw,
        const double* __restrict__ ninv, const double* __restrict__ einv) {
    int wid = (blockIdx.x * 256 + threadIdx.x) >> 6;
    int l = threadIdx.x & 63;
    int nw = gridDim.x * 4;
    double w2[NCH][2];                       // hoisted: uniform across candidates
    #pragma unroll
    for (int c = 0; c < NCH; ++c) {
        float2 wc2 = *(const float2*)&cw[c * DIM + 2 * l];
        w2[c][0] = (double)wc2.x * (double)wc2.x;
        w2[c][1] = (double)wc2.y * (double)wc2.y;
    }
    for (int s = 0; s < NSEG; ++s) {
        int nc = (int)(segc[s * SEGSTR] & 0xffffffffull); if (nc > CAPSEG) nc = CAPSEG;
        const int* ci = cidx + s * CAPSEG;
        double* cv = cval + s * CAPSEG;
        for (int i = wid; i < nc; i += nw) {
            int idx = ci[i];
            int n = idx >> 12, m = idx & (M_EDGES - 1);
            float2  x2 = *(const float2*)&X[n * DIM + 2 * l];
            double2 e2 = *(const double2*)&eXd[m * DIM + 2 * l];
            double p0 = (double)x2.x * e2.x;
            double p1 = (double)x2.y * e2.y;
            double dt0 = p0 * w2[0][0] + p1 * w2[0][1];
            double dt1 = p0 * w2[1][0] + p1 * w2[1][1];
            double dt2 = p0 * w2[2][0] + p1 * w2[2][1];
            double dt3 = p0 * w2[3][0] + p1 * w2[3][1];
            #pragma unroll
            for (int sh = 1; sh < 64; sh <<= 1) {
                dt0 += __shfl_xor(dt0, sh);
                dt1 += __shfl_xor(dt1, sh);
                dt2 += __shfl_xor(dt2, sh);
                dt3 += __shfl_xor(dt3, sh);
            }
            if (l == 0) {
                const double* nv = &ninv[n * NCH];
                const double* ev = &einv[m * NCH];
                cv[i] = 0.25 * (dt0 * nv[0] * ev[0] + dt1 * nv[1] * ev[1]
                              + dt2 * nv[2] * ev[2] + dt3 * nv[3] * ev[3]);
            }
        }
    }
}

// ---- 14. fine fp64 histogram of band values, per segment ----
__global__ __launch_bounds__(256) void k_fhist(const unsigned long long* __restrict__ segc,
                                               const double* __restrict__ cval,
                                               const int* __restrict__ scl,
                                               int* __restrict__ fh) {
    int bstar = scl[0];
    for (int s = 0; s < NSEG; ++s) {
        int nc = (int)(segc[s * SEGSTR] & 0xffffffffull); if (nc > CAPSEG) nc = CAPSEG;
        const double* cv = cval + s * CAPSEG;
        for (int i = blockIdx.x * 256 + threadIdx.x; i < nc; i += 256 * 256)
            atomicAdd(&fh[fbin_of(cv[i], bstar)], 1);
    }
}

// ---- 15. find fine cutoff f* for target T = NUM_ADD - G1 ----
__global__ __launch_bounds__(1024) void k_ffind(const int* __restrict__ fh, int* __restrict__ scl) {
    __shared__ int part[1024];
    int T = NUM_ADD - scl[1];            // >= 1 by construction of b*
    int t = threadIdx.x;
    int loc[32]; int s = 0;
    for (int j = 0; j < 32; ++j) { loc[j] = fh[t * 32 + j]; s += loc[j]; }
    part[t] = s;
    __syncthreads();
    if (t == 0) { int acc = 0; for (int i = 1023; i >= 0; --i) { int v = part[i]; part[i] = acc; acc += v; } }
    __syncthreads();
    int run = part[t];
    for (int j = 31; j >= 0; --j) {
        int h = loc[j];
        run += h;
        if (run >= T && run - h < T) { scl[4] = t * 32 + j; scl[5] = run - h; }
    }
}

// ---- 16. write band candidates strictly above the fine cutoff bin ----
__global__ __launch_bounds__(256) void k_write(
        const unsigned long long* __restrict__ segc, const int* __restrict__ cidx,
        const double* __restrict__ cval, const int* __restrict__ scl,
        const float* __restrict__ prob, const float* __restrict__ eps,
        float* __restrict__ out) {
    int fs = scl[4], bstar = scl[0];
    for (int s = 0; s < NSEG; ++s) {
        int nc = (int)(segc[s * SEGSTR] & 0xffffffffull); if (nc > CAPSEG) nc = CAPSEG;
        const int* ci = cidx + s * CAPSEG;
        const double* cv = cval + s * CAPSEG;
        for (int i = blockIdx.x * 256 + threadIdx.x; i < nc; i += 256 * 256) {
            if (fbin_of(cv[i], bstar) > fs) {
                int idx = ci[i];
                out[idx] = hard_mask(prob[idx], eps[idx]);
            }
        }
    }
}

// ---- 17. exact tie-break inside the single ambiguous fine bin ----
__global__ __launch_bounds__(256) void k_tie(
        const unsigned long long* __restrict__ segc, const int* __restrict__ cidx,
        const double* __restrict__ cval, const int* __restrict__ scl,
        const float* __restrict__ prob, const float* __restrict__ eps,
        float* __restrict__ out) {
    __shared__ double mv[256];
    __shared__ int    mi[256];
    __shared__ int    cnt;
    int T = NUM_ADD - scl[1];
    int fs = scl[4], G1f = scl[5], bstar = scl[0];
    int t = threadIdx.x;
    if (t == 0) cnt = 0;
    __syncthreads();
    for (int s = 0; s < NSEG; ++s) {
        int nc = (int)(segc[s * SEGSTR] & 0xffffffffull); if (nc > CAPSEG) nc = CAPSEG;
        const double* cv = cval + s * CAPSEG;
        const int* ci = cidx + s * CAPSEG;
        for (int i = t; i < nc; i += 256) {
            if (fbin_of(cv[i], bstar) == fs) {
                int sl = atomicAdd(&cnt, 1);
                if (sl < 256) { mv[sl] = cv[i]; mi[sl] = ci[i]; }
            }
        }
    }
    __syncthreads();
    int nm = min(cnt, 256);
    for (int k = t; k < nm; k += 256) {
        double v = mv[k]; int idx = mi[k];
        int rank = G1f;
        for (int j = 0; j < nm; ++j)
            rank += (mv[j] > v || (mv[j] == v && mi[j] < idx)) ? 1 : 0;
        if (rank < T)
            out[idx] = hard_mask(prob[idx], eps[idx]);
    }
}

extern "C" void kernel_launch(void* const* d_in, const int* in_sizes, int n_in,
                              void* d_out, int out_size, void* d_ws, size_t ws_size,
                              hipStream_t stream) {
    const float* X    = (const float*)d_in[0];
    const int*   Vv   = (const int*)d_in[2];
    const int*   E    = (const int*)d_in[3];
    const float* prob = (const float*)d_in[4];
    const float* cw   = (const float*)d_in[5];
    const float* eps  = (const float*)d_in[6];
    float* out = (float*)d_out;
    char*  ws  = (char*)d_ws;

    double*             eXd   = (double*)(ws + EXD_OFF);
    unsigned short*     Afc   = (unsigned short*)(ws + AFC_OFF);
    unsigned short*     Bfc   = (unsigned short*)(ws + BFC_OFF);
    int*                bkt   = (int*)(ws + BKT_OFF);
    double*             cval  = (double*)(ws + CVAL_OFF);
    int*                cidx  = (int*)(ws + CIDX_OFF);
    int*                cidx2 = (int*)(ws + CIDX2_OFF);
    int*                cnt   = (int*)(ws + CNT_OFF);
    int*                offs  = (int*)(ws + OFFS_OFF);
    int*                cur   = (int*)(ws + CUR_OFF);
    int*                hist  = (int*)(ws + HIST_OFF);
    int*                fh    = (int*)(ws + FHIST_OFF);
    int*                scl   = (int*)(ws + SCL_OFF);
    unsigned long long* segc  = (unsigned long long*)(ws + SEGC_OFF);
    double*             ninv  = (double*)(ws + NINV_OFF);
    double*             einv  = (double*)(ws + EINV_OFF);

    hipMemsetAsync(ws + CNT_OFF, 0, (size_t)ZERO_BYTES, stream);

    k_count<<<NNZ_K / 256, 256, 0, stream>>>(E, cnt);
    k_scan<<<1, 256, 0, stream>>>(cnt, offs);
    k_fill<<<NNZ_K / 256, 256, 0, stream>>>(E, offs, cur, bkt);
    k_edge_mean<<<M_EDGES, 128, 0, stream>>>(Vv, cnt, offs, bkt, X, eXd);
    k_fc<float><<<N_NODES, 128, 0, stream>>>(X, cw, Afc, ninv);
    k_fc<double><<<M_EDGES, 128, 0, stream>>>(eXd, cw, Bfc, einv);
    dim3 gg(M_EDGES / 128, N_NODES / 128);
    k_gemm_mfma<<<gg, 256, 0, stream>>>(Afc, Bfc, out);
    k_mask<<<NNZ_K / 256, 256, 0, stream>>>(Vv, E, out);
    k_hist_coarse<<<1024, 256, 0, stream>>>((const float4*)out, hist);
    k_findcut<<<1, 256, 0, stream>>>(hist, scl);
    k_collect<<<4096, 256, 0, stream>>>((float4*)out, scl, segc, cidx, cidx2);
    k_scatter<<<NNZ_K / 256, 256, 0, stream>>>(Vv, E, prob, eps, out);
    k_selc<<<128, 256, 0, stream>>>(segc, cidx2, prob, eps, out);
    k_exact<<<1024, 256, 0, stream>>>(segc, cidx, cval, X, eXd, cw, ninv, einv);
    k_fhist<<<256, 256, 0, stream>>>(segc, cval, scl, fh);
    k_ffind<<<1, 1024, 0, stream>>>(fh, scl);
    k_write<<<256, 256, 0, stream>>>(segc, cidx, cval, scl, prob, eps, out);
    k_tie<<<1, 256, 0, stream>>>(segc, cidx, cval, scl, prob, eps, out);
}